// Round 7
// baseline (144.686 us; speedup 1.0000x reference)
//
#include <hip/hip_runtime.h>
#include <hip/hip_bf16.h>
#include <stdint.h>

// Problem dims (fixed by setup_inputs)
#define B_N 4096
#define S_N 8192
#define KX  256
#define KY  128
#define BM  128
#define BN  128

#define INV_LN2 1.4426950408889634f
#define LN2_F   0.6931471805599453f

typedef __bf16 bf16x8 __attribute__((ext_vector_type(8)));
typedef float  f32x4  __attribute__((ext_vector_type(4)));

// native v_exp_f32 / v_log_f32 (base-2) — NOT __exp2f (glibc name clash)
__device__ __forceinline__ float exp2g(float x) { return __builtin_amdgcn_exp2f(x); }
__device__ __forceinline__ float log2g(float x) { return __builtin_amdgcn_logf(x); }

// ---- workspace byte offsets ----
#define OFF_XH   ((size_t)0)            // 4096*256*2 = 2 MB  (scaled by 1/ln2)
#define OFF_YH   ((size_t)2097152)      // 4096*128*2 = 1 MB  (scaled by 1/ln2)
#define OFF_SXH  ((size_t)3145728)      // 8192*256*2 = 4 MB  (unscaled)
#define OFF_SYH  ((size_t)7340032)      // 8192*128*2 = 2 MB  (unscaled)
#define OFF_NX   ((size_t)9437184)      // 4096 f32, pre-multiplied by -0.5/ln2
#define OFF_NY   (OFF_NX + 16384)
#define OFF_NSX  (OFF_NY + 16384)       // 8192 f32, pre-multiplied by -0.5/ln2
#define OFF_NSY  (OFF_NSX + 32768)
#define OFF_PART (OFF_NSY + 32768)      // [3][64][4096] float2 (log2-domain m,s)
#define OFF_BSUM (OFF_PART + (size_t)3*64*4096*2*4)   // 128 f32

__device__ __forceinline__ void gl2lds16(const void* g, void* l) {
  // async global->LDS, 16B per lane; LDS dest = wave-uniform base + lane*16
  typedef const __attribute__((address_space(1))) unsigned int* gp_t;
  typedef __attribute__((address_space(3))) unsigned int* lp_t;
  __builtin_amdgcn_global_load_lds((gp_t)g, (lp_t)l, 16, 0, 0);
}

__device__ __forceinline__ unsigned short f2bf(float f) {
  unsigned u = __builtin_bit_cast(unsigned, f);
  return (unsigned short)((u + 0x7fffu + ((u >> 16) & 1u)) >> 16);
}

// ---- preprocessing: fp32 -> bf16 + norms. Batch mats scaled by 1/ln2 so the
// GEMM result is already in log2 domain; norms stored pre-multiplied -0.5/ln2.
__global__ __launch_bounds__(256) void conv_all(const float* __restrict__ x,
                                                const float* __restrict__ y,
                                                const float* __restrict__ xs,
                                                const float* __restrict__ ys,
                                                char* __restrict__ ws) {
  int b    = blockIdx.x;
  int wave = threadIdx.x >> 6;
  int lane = threadIdx.x & 63;
  const float* src; unsigned short* hi; float* nrm;
  int K, row; float scale;
  if (b < 1024) {
    src = x;  hi = (unsigned short*)(ws + OFF_XH);
    nrm = (float*)(ws + OFF_NX); K = 256; row = b * 4 + wave; scale = INV_LN2;
  } else if (b < 2048) {
    src = y;  hi = (unsigned short*)(ws + OFF_YH);
    nrm = (float*)(ws + OFF_NY); K = 128; row = (b - 1024) * 4 + wave; scale = INV_LN2;
  } else if (b < 4096) {
    src = xs; hi = (unsigned short*)(ws + OFF_SXH);
    nrm = (float*)(ws + OFF_NSX); K = 256; row = (b - 2048) * 4 + wave; scale = 1.0f;
  } else {
    src = ys; hi = (unsigned short*)(ws + OFF_SYH);
    nrm = (float*)(ws + OFF_NSY); K = 128; row = (b - 4096) * 4 + wave; scale = 1.0f;
  }
  float acc = 0.f;
  if (K == 256) {
    float4 v = ((const float4*)(src + (size_t)row * 256))[lane];
    float vv[4] = {v.x, v.y, v.z, v.w};
    ushort4 h4;
    unsigned short* hp = (unsigned short*)&h4;
    #pragma unroll
    for (int k = 0; k < 4; ++k) {
      acc = fmaf(vv[k], vv[k], acc);
      hp[k] = f2bf(vv[k] * scale);
    }
    ((ushort4*)(hi + (size_t)row * 256))[lane] = h4;
  } else {
    float2 v = ((const float2*)(src + (size_t)row * 128))[lane];
    float vv[2] = {v.x, v.y};
    ushort2 h2;
    unsigned short* hp = (unsigned short*)&h2;
    #pragma unroll
    for (int k = 0; k < 2; ++k) {
      acc = fmaf(vv[k], vv[k], acc);
      hp[k] = f2bf(vv[k] * scale);
    }
    ((ushort2*)(hi + (size_t)row * 128))[lane] = h2;
  }
  #pragma unroll
  for (int o = 32; o > 0; o >>= 1) acc += __shfl_down(acc, o);
  if (lane == 0) nrm[row] = acc * (-0.5f * INV_LN2);
}

// ---- main: fused dual-GEMM + log2-domain lse epilogue ----
// 512 thr = 8 waves (4x2). Pair-chunk double buffer: each buffer holds 2
// 16-KB chunks (A 8K + B 8K each); barrier every 2 chunks -> 6 barriers,
// 16-MFMA cover per drain. LDS 2x32 KB = 64 KB -> 2 blocks/CU.
// Chunk layout: 128 rows x 64 B; granule g at slot g ^ ((r>>1)&3).
__global__ __launch_bounds__(512, 4) void mie_main(const char* __restrict__ ws,
                                                   float* __restrict__ part) {
  __shared__ __align__(16) char smem[65536];

  const int tid  = threadIdx.x;
  const int lane = tid & 63;
  const int wave = tid >> 6;
  const int c    = lane & 15;
  const int q    = lane >> 4;
  const int wm   = wave >> 1;   // 0..3
  const int wn   = wave & 1;    // 0..1

  const int b     = blockIdx.x;
  const int xcd   = b & 7;
  const int w     = b >> 3;              // 0..255
  const int bm_t  = w & 31;              // fast: A streams, B stays L2-resident
  const int sn_t  = xcd * 8 + (w >> 5);  // 0..63
  const int bm0   = bm_t * BM;
  const int sn0   = sn_t * BN;

  const char* xh  = ws + OFF_XH;
  const char* yh  = ws + OFF_YH;
  const char* sxh = ws + OFF_SXH;
  const char* syh = ws + OFF_SYH;
  const float* nx  = (const float*)(ws + OFF_NX);
  const float* ny  = (const float*)(ws + OFF_NY);
  const float* nsx = (const float*)(ws + OFF_NSX);
  const float* nsy = (const float*)(ws + OFF_NSY);

  // stage one 16-KB chunk (A 8K, B 8K) at LDS base
  auto stage = [&](int kc, char* base) {
    const char *ah, *bh; int rb, k0b;
    if (kc < 8) { ah = xh; bh = sxh; rb = 512; k0b = kc * 64; }
    else        { ah = yh; bh = syh; rb = 256; k0b = (kc - 8) * 64; }
    int l  = wave * 64 + lane;           // linear 16B slot 0..511
    int r  = l >> 2;
    int sl = l & 3;
    int g  = sl ^ ((r >> 1) & 3);
    size_t kofs = (size_t)k0b + (size_t)g * 16;
    size_t goA  = (size_t)(bm0 + r) * rb + kofs;
    size_t goB  = (size_t)(sn0 + r) * rb + kofs;
    char* dst = base + wave * 1024;      // wave-uniform + lane*16
    gl2lds16(ah + goA, dst);
    gl2lds16(bh + goB, dst + 8192);
  };

  // fragment LDS offsets (row stride 64 B, swizzled slot)
  const int slot = (q ^ ((c >> 1) & 3)) * 16;
  int aoff[2], boff[4];
  #pragma unroll
  for (int i = 0; i < 2; ++i) aoff[i] = (wm * 32 + i * 16 + c) * 64 + slot;
  #pragma unroll
  for (int j = 0; j < 4; ++j) boff[j] = (wn * 64 + j * 16 + c) * 64 + slot;

  f32x4 accx[2][4], accy[2][4];
  #pragma unroll
  for (int i = 0; i < 2; ++i)
    #pragma unroll
    for (int j = 0; j < 4; ++j) {
      accx[i][j] = (f32x4){0.f,0.f,0.f,0.f};
      accy[i][j] = (f32x4){0.f,0.f,0.f,0.f};
    }

  stage(0, smem);
  stage(1, smem + 16384);
  __syncthreads();

  #pragma unroll
  for (int p = 0; p < 6; ++p) {
    if (p < 5) {
      char* nb = smem + ((p + 1) & 1) * 32768;
      stage(2 * p + 2, nb);
      stage(2 * p + 3, nb + 16384);
    }
    const char* bufb = smem + (p & 1) * 32768;
    #pragma unroll
    for (int h = 0; h < 2; ++h) {
      int kc = 2 * p + h;
      const char* base = bufb + h * 16384;
      bf16x8 Ah[2], Bh[4];
      #pragma unroll
      for (int i = 0; i < 2; ++i) Ah[i] = *(const bf16x8*)(base + aoff[i]);
      #pragma unroll
      for (int j = 0; j < 4; ++j) Bh[j] = *(const bf16x8*)(base + 8192 + boff[j]);
      if (kc < 8) {
        #pragma unroll
        for (int i = 0; i < 2; ++i)
          #pragma unroll
          for (int j = 0; j < 4; ++j)
            accx[i][j] = __builtin_amdgcn_mfma_f32_16x16x32_bf16(Ah[i], Bh[j], accx[i][j], 0, 0, 0);
      } else {
        #pragma unroll
        for (int i = 0; i < 2; ++i)
          #pragma unroll
          for (int j = 0; j < 4; ++j)
            accy[i][j] = __builtin_amdgcn_mfma_f32_16x16x32_bf16(Ah[i], Bh[j], accy[i][j], 0, 0, 0);
      }
    }
    __syncthreads();
  }

  // ---- epilogue (log2 domain): v = acc + hrow + hcol; max-first lse2 ----
  float hxv[2][4], hyv[2][4];
  #pragma unroll
  for (int i = 0; i < 2; ++i)
    #pragma unroll
    for (int r = 0; r < 4; ++r) {
      int rr = bm0 + wm * 32 + i * 16 + q * 4 + r;
      hxv[i][r] = nx[rr];
      hyv[i][r] = ny[rr];
    }
  float hsxv[4], hsyv[4];
  #pragma unroll
  for (int j = 0; j < 4; ++j) {
    int cc = sn0 + wn * 64 + j * 16 + c;
    hsxv[j] = nsx[cc];
    hsyv[j] = nsy[cc];
  }

  // per-(stream,row_local,wn) partials in LDS: float2 arr[3][128][2]
  float2* xch = (float2*)smem;
  #pragma unroll
  for (int i = 0; i < 2; ++i) {
    #pragma unroll
    for (int r = 0; r < 4; ++r) {
      float vx[4], vy[4];
      #pragma unroll
      for (int j = 0; j < 4; ++j) {
        vx[j] = accx[i][j][r] + hxv[i][r] + hsxv[j];
        vy[j] = accy[i][j][r] + hyv[i][r] + hsyv[j];
      }
      int rl = wm * 32 + i * 16 + q * 4 + r;
      #pragma unroll
      for (int st = 0; st < 3; ++st) {
        float v0 = (st == 0) ? vx[0] + vy[0] : (st == 1 ? vx[0] : vy[0]);
        float v1 = (st == 0) ? vx[1] + vy[1] : (st == 1 ? vx[1] : vy[1]);
        float v2 = (st == 0) ? vx[2] + vy[2] : (st == 1 ? vx[2] : vy[2]);
        float v3 = (st == 0) ? vx[3] + vy[3] : (st == 1 ? vx[3] : vy[3]);
        float m = fmaxf(fmaxf(v0, v1), fmaxf(v2, v3));
        #pragma unroll
        for (int msk = 1; msk < 16; msk <<= 1) m = fmaxf(m, __shfl_xor(m, msk));
        float s = exp2g(v0 - m) + exp2g(v1 - m) + exp2g(v2 - m) + exp2g(v3 - m);
        #pragma unroll
        for (int msk = 1; msk < 16; msk <<= 1) s += __shfl_xor(s, msk);
        if (c == 0) xch[(st * 128 + rl) * 2 + wn] = (float2){m, s};
      }
    }
  }
  __syncthreads();

  // merge the two wn halves; write coalesced partials: [3][64][4096] float2
  if (tid < 384) {
    int st = tid >> 7;
    int rl = tid & 127;
    float2 a = xch[(st * 128 + rl) * 2 + 0];
    float2 bb = xch[(st * 128 + rl) * 2 + 1];
    float m = fmaxf(a.x, bb.x);
    float s = a.y * exp2g(a.x - m) + bb.y * exp2g(bb.x - m);
    size_t idx = ((size_t)st * 64 + sn_t) * B_N + (bm0 + rl);
    ((float2*)part)[idx] = (float2){m, s};
  }
}

// ---- finalize stage 1: 128 blocks x 256 thr; 32 rows/block, 8 lanes/row ----
__global__ __launch_bounds__(256) void fin1(const float* __restrict__ part,
                                            float* __restrict__ bsum) {
  __shared__ float red[4];
  int tid = threadIdx.x;
  int sub = tid & 7;
  int row = blockIdx.x * 32 + (tid >> 3);
  float v[3];
  #pragma unroll
  for (int j = 0; j < 3; ++j) {
    float m = -__builtin_inff(), s = 0.f;
    #pragma unroll
    for (int pp = 0; pp < 8; ++pp) {
      int p = sub * 8 + pp;
      float2 a = ((const float2*)part)[((size_t)j * 64 + p) * B_N + row];
      float nm = fmaxf(m, a.x);
      s = s * exp2g(m - nm) + a.y * exp2g(a.x - nm);
      m = nm;
    }
    #pragma unroll
    for (int msk = 1; msk < 8; msk <<= 1) {
      float om = __shfl_xor(m, msk);
      float os = __shfl_xor(s, msk);
      float nm = fmaxf(m, om);
      s = s * exp2g(m - nm) + os * exp2g(om - nm);
      m = nm;
    }
    v[j] = m + log2g(s);
  }
  float local = (sub == 0) ? (v[0] - v[1] - v[2]) : 0.f;
  #pragma unroll
  for (int o = 32; o > 0; o >>= 1) local += __shfl_down(local, o);
  int wv = tid >> 6, lane = tid & 63;
  if (lane == 0) red[wv] = local;
  __syncthreads();
  if (tid == 0) bsum[blockIdx.x] = red[0] + red[1] + red[2] + red[3];
}

// ---- finalize stage 2: mean over 4096 rows (128 block sums), back to ln ----
__global__ void fin2(const float* __restrict__ bsum, float* __restrict__ out) {
  int t = threadIdx.x;
  float a = bsum[t] + bsum[t + 64];
  #pragma unroll
  for (int o = 32; o > 0; o >>= 1) a += __shfl_down(a, o);
  if (t == 0) out[0] = a * (LN2_F / (float)B_N);
}

extern "C" void kernel_launch(void* const* d_in, const int* in_sizes, int n_in,
                              void* d_out, int out_size, void* d_ws, size_t ws_size,
                              hipStream_t stream) {
  (void)in_sizes; (void)n_in; (void)out_size; (void)ws_size;
  const float* x  = (const float*)d_in[0];
  const float* y  = (const float*)d_in[1];
  const float* xs = (const float*)d_in[2];
  const float* ys = (const float*)d_in[3];
  char* ws = (char*)d_ws;

  conv_all<<<6144, 256, 0, stream>>>(x, y, xs, ys, ws);
  mie_main<<<2048, 512, 0, stream>>>(ws, (float*)(ws + OFF_PART));
  fin1<<<128, 256, 0, stream>>>((const float*)(ws + OFF_PART), (float*)(ws + OFF_BSUM));
  fin2<<<1, 64, 0, stream>>>((const float*)(ws + OFF_BSUM), (float*)d_out);
}